// Round 2
// baseline (539.981 us; speedup 1.0000x reference)
//
#include <hip/hip_runtime.h>

// LSTMOnline: E=1024, H=4096, batch=1, single step. All tensors fp32 (per
// reference). Memory-bound GEMV chain: ~544 MiB weight reads -> ~90 us floor.
// Structure: 3 kernels (in-proj, fused gates+cell, out-proj), one wave per
// output row, float4 coalesced loads, wave-64 shuffle reduction.

#define E_DIM 1024
#define H_DIM 4096

__device__ __forceinline__ float wave_reduce(float v) {
#pragma unroll
    for (int off = 32; off > 0; off >>= 1) v += __shfl_down(v, off, 64);
    return v;
}

// Stage 1: xi[row] = dot(W_in[row,:E], x) + b_in[row].  One wave per row.
__global__ __launch_bounds__(256) void k_in_proj(
    const float* __restrict__ W, const float* __restrict__ x,
    const float* __restrict__ b, float* __restrict__ xi)
{
    const int lane = threadIdx.x & 63, w = threadIdx.x >> 6;
    const int row = blockIdx.x * 4 + w;
    const float* Wr = W + (size_t)row * E_DIM;
    float acc = 0.f;
#pragma unroll
    for (int c = 0; c < 4; ++c) {                 // 64 lanes * 4 floats * 4 = 1024
        const int e = (lane + c * 64) * 4;
        const float4 wv = *(const float4*)(Wr + e);
        const float4 xv = *(const float4*)(x + e);
        acc += wv.x * xv.x + wv.y * xv.y + wv.z * xv.z + wv.w * xv.w;
    }
    acc = wave_reduce(acc);
    if (lane == 0) xi[row] = acc + b[row];
}

// Stage 2+3 fused: block = one hidden index h; wave g in {i,f,g,o} computes
// gates[g*H+h] = W_ih[row]·xi + W_hh[row]·h0 + b_ih[row] + b_hh[row];
// thread 0 then applies the LSTM cell and writes h1 (fp32 out + fp32 scratch)
// and c1.
__global__ __launch_bounds__(256) void k_gates_cell(
    const float* __restrict__ Wih, const float* __restrict__ Whh,
    const float* __restrict__ xi, const float* __restrict__ h0,
    const float* __restrict__ c0,
    const float* __restrict__ bih, const float* __restrict__ bhh,
    float* __restrict__ h1_out, float* __restrict__ c1_out,
    float* __restrict__ h1f)
{
    const int tid = threadIdx.x, lane = tid & 63, g = tid >> 6;
    const int hidx = blockIdx.x;
    const int row = g * H_DIM + hidx;
    const float* W1 = Wih + (size_t)row * H_DIM;
    const float* W2 = Whh + (size_t)row * H_DIM;
    float acc = 0.f;
#pragma unroll
    for (int c = 0; c < 16; ++c) {                // 64 lanes * 4 floats * 16 = 4096
        const int e = (lane + c * 64) * 4;
        const float4 w1 = *(const float4*)(W1 + e);
        const float4 w2 = *(const float4*)(W2 + e);
        const float4 xv = *(const float4*)(xi + e);
        const float4 hv = *(const float4*)(h0 + e);
        acc += w1.x * xv.x + w1.y * xv.y + w1.z * xv.z + w1.w * xv.w;
        acc += w2.x * hv.x + w2.y * hv.y + w2.z * hv.z + w2.w * hv.w;
    }
    acc = wave_reduce(acc);
    __shared__ float gv[4];
    if (lane == 0) gv[g] = acc + bih[row] + bhh[row];
    __syncthreads();
    if (tid == 0) {
        const float ig = 1.f / (1.f + expf(-gv[0]));
        const float fg = 1.f / (1.f + expf(-gv[1]));
        const float gg = tanhf(gv[2]);
        const float og = 1.f / (1.f + expf(-gv[3]));
        const float cp = c0[hidx];
        const float c1 = fg * cp + ig * gg;
        const float h1 = og * tanhf(c1);
        c1_out[hidx] = c1;
        h1_out[hidx] = h1;
        h1f[hidx]    = h1;
    }
}

// Stage 4: out[row] = dot(W_out[row,:H], h1) + b_out[row].  One wave per row.
__global__ __launch_bounds__(256) void k_out_proj(
    const float* __restrict__ W, const float* __restrict__ h1f,
    const float* __restrict__ b, float* __restrict__ out)
{
    const int lane = threadIdx.x & 63, w = threadIdx.x >> 6;
    const int row = blockIdx.x * 4 + w;
    const float* Wr = W + (size_t)row * H_DIM;
    float acc = 0.f;
#pragma unroll
    for (int c = 0; c < 16; ++c) {
        const int e = (lane + c * 64) * 4;
        const float4 wv = *(const float4*)(Wr + e);
        const float4 xv = *(const float4*)(h1f + e);
        acc += wv.x * xv.x + wv.y * xv.y + wv.z * xv.z + wv.w * xv.w;
    }
    acc = wave_reduce(acc);
    if (lane == 0) out[row] = acc + b[row];
}

extern "C" void kernel_launch(void* const* d_in, const int* in_sizes, int n_in,
                              void* d_out, int out_size, void* d_ws, size_t ws_size,
                              hipStream_t stream) {
    const float* x     = (const float*)d_in[0];
    const float* h0    = (const float*)d_in[1];
    const float* c0    = (const float*)d_in[2];
    const float* W_in  = (const float*)d_in[3];
    const float* b_in  = (const float*)d_in[4];
    const float* W_ih  = (const float*)d_in[5];
    const float* W_hh  = (const float*)d_in[6];
    const float* b_ih  = (const float*)d_in[7];
    const float* b_hh  = (const float*)d_in[8];
    const float* W_out = (const float*)d_in[9];
    const float* b_out = (const float*)d_in[10];

    float* out = (float*)d_out;                    // [0, 1024)        out
    float* h1o = out + E_DIM;                      // [1024, 5120)     h1
    float* c1o = out + E_DIM + H_DIM;              // [5120, 9216)     c1

    float* xi  = (float*)d_ws;                     // 4096 fp32 scratch
    float* h1f = xi + H_DIM;                       // 4096 fp32 scratch

    k_in_proj<<<H_DIM / 4, 256, 0, stream>>>(W_in, x, b_in, xi);
    k_gates_cell<<<H_DIM, 256, 0, stream>>>(W_ih, W_hh, xi, h0, c0,
                                            b_ih, b_hh, h1o, c1o, h1f);
    k_out_proj<<<E_DIM / 4, 256, 0, stream>>>(W_out, h1f, b_out, out);
}